// Round 2
// baseline (41.446 us; speedup 1.0000x reference)
//
#include <hip/hip_runtime.h>

// gen_En gather-form: En[g] = sum_{i covering g} sum_m eta[i,m]*U[i,m]*Ey[i,m,f]
//   eta = neff/(neff+1), f = g - 64 - 128*i in [0,1024), overlap factor 8.
// Each Ey element is consumed exactly once; no atomics; no zero-init pass
// (every output float4 is written exactly once).
//
// This version: 2048 outputs/block, each thread owns two float4s (g0, g0+1024).
// Window trick: position g0+1024 at waveguide i+8 uses the SAME fragment
// offset f as position g0 at waveguide i -> one fused loop, 12 independent
// nontemporal loads per iteration (2x memory-level parallelism vs round 1).

#define MODES 6
#define NWG 8192
#define EY_SIZE 1024
#define TOTAL_SIZE ((NWG + 8) * 128)        // 1,049,600
#define BLK_OUT 2048
#define NBLOCKS ((TOTAL_SIZE + BLK_OUT - 1) / BLK_OUT)   // 513

typedef float f4 __attribute__((ext_vector_type(4)));

__global__ __launch_bounds__(256) void gen_en_gather2(
    const float* __restrict__ U,
    const float* __restrict__ neff,
    const float* __restrict__ Ey,
    float* __restrict__ En)
{
    // Block spans 2048 outputs -> at most 24 waveguides contribute.
    __shared__ float w[24 * MODES];          // 144 floats

    const int base = blockIdx.x * BLK_OUT;
    const int i_lo_raw = ((base - 64) >> 7) - 7;   // may be negative (block 0)

    const int t = threadIdx.x;
    if (t < 24 * MODES) {
        const int di = t / MODES;
        const int m  = t - di * MODES;
        const int i  = i_lo_raw + di;
        float v = 0.0f;
        if (i >= 0 && i < NWG) {
            const float nf = neff[i * MODES + m];
            v = nf / (nf + 1.0f) * U[i * MODES + m];    // eta * U
        }
        w[t] = v;
    }
    __syncthreads();

    const int g0 = base + (t << 2);          // multiple of 4
    const int g1 = g0 + 1024;
    const int tg = g0 - 64;                  // >= -64
    const int ihi   = tg >> 7;               // floor(tg/128) (arith shift)
    const int ibase = ihi - 7;
    const int dibase = ibase - i_lo_raw;     // in [0,8]

    f4 acc0 = (f4)0.0f;
    f4 acc1 = (f4)0.0f;

    #pragma unroll
    for (int k = 0; k < 8; ++k) {
        const int i0 = ibase + k;            // window for g0
        const int i1 = i0 + 8;               // same-f window for g1
        const int f  = tg - i0 * 128;        // in [0,1020], multiple of 4
        // Out-of-range waveguides: weight is 0 (set above); clamp the
        // address so the (discarded) load stays in-bounds. Branch-free.
        const int i0c = i0 < 0 ? 0 : (i0 > NWG - 1 ? NWG - 1 : i0);
        const int i1c = i1 < 0 ? 0 : (i1 > NWG - 1 ? NWG - 1 : i1);
        const float* e0 = Ey + (size_t)i0c * (MODES * EY_SIZE) + f;
        const float* e1 = Ey + (size_t)i1c * (MODES * EY_SIZE) + f;
        const int wb0 = (dibase + k) * MODES;
        const int wb1 = wb0 + 8 * MODES;
        #pragma unroll
        for (int m = 0; m < MODES; ++m) {
            const f4 a = __builtin_nontemporal_load(
                reinterpret_cast<const f4*>(e0 + m * EY_SIZE));
            const f4 b = __builtin_nontemporal_load(
                reinterpret_cast<const f4*>(e1 + m * EY_SIZE));
            const float w0 = w[wb0 + m];
            const float w1 = w[wb1 + m];
            acc0 += w0 * a;
            acc1 += w1 * b;
        }
    }

    __builtin_nontemporal_store(acc0, reinterpret_cast<f4*>(En + g0));
    if (g1 < TOTAL_SIZE)                     // only last block's upper half
        __builtin_nontemporal_store(acc1, reinterpret_cast<f4*>(En + g1));
}

extern "C" void kernel_launch(void* const* d_in, const int* in_sizes, int n_in,
                              void* d_out, int out_size, void* d_ws, size_t ws_size,
                              hipStream_t stream) {
    // inputs (setup_inputs order): hs (unused), U, neff, Ey — all float32
    const float* U    = (const float*)d_in[1];
    const float* neff = (const float*)d_in[2];
    const float* Ey   = (const float*)d_in[3];
    float* En = (float*)d_out;

    gen_en_gather2<<<NBLOCKS, 256, 0, stream>>>(U, neff, Ey, En);
}

// Round 3
// 38.131 us; speedup vs baseline: 1.0869x; 1.0869x over previous
//
#include <hip/hip_runtime.h>

// gen_En gather-form: En[g] = sum_{i covering g} sum_m eta[i,m]*U[i,m]*Ey[i,m,f]
//   eta = neff/(neff+1), f = g - 64 - 128*i in [0,1024), overlap factor 8.
// Each Ey element is consumed exactly once; no atomics; no zero-init pass
// (every output float4 is written exactly once -> poisoned d_out fully covered).
//
// Round-1 geometry (1025 blocks x 256 threads, one float4/thread = best TLP),
// plus: constant-8 branch-free window loop (full unroll, zero weights + clamped
// addresses for edge blocks) and nontemporal Ey loads (single-use stream).

#define MODES 6
#define NWG 8192
#define EY_SIZE 1024
#define TOTAL_SIZE ((NWG + 8) * 128)     // 1,049,600
#define NBLOCKS (TOTAL_SIZE / 1024)      // 1025, exact tiling

typedef float f4 __attribute__((ext_vector_type(4)));

__global__ __launch_bounds__(256) void gen_en_gather3(
    const float* __restrict__ U,
    const float* __restrict__ neff,
    const float* __restrict__ Ey,
    float* __restrict__ En)
{
    // Windows touching this block's 1024 outputs span 16 waveguides.
    __shared__ float w[16 * MODES];      // 96 floats

    const int g_blk = blockIdx.x << 10;
    const int i_lo_raw = ((g_blk - 64) >> 7) - 7;   // may be negative (block 0)

    const int t = threadIdx.x;
    if (t < 16 * MODES) {
        const int di = t / MODES;
        const int m  = t - di * MODES;
        const int i  = i_lo_raw + di;
        float v = 0.0f;
        if (i >= 0 && i < NWG) {
            const float nf = neff[i * MODES + m];
            v = nf / (nf + 1.0f) * U[i * MODES + m];    // eta * U
        }
        w[t] = v;
    }
    __syncthreads();

    const int g0 = g_blk + (t << 2);     // multiple of 4
    const int tg = g0 - 64;              // >= -64
    const int ihi   = tg >> 7;           // floor(tg/128), arithmetic shift ok
    const int ibase = ihi - 7;
    const int dibase = ibase - i_lo_raw; // in [0,8]

    f4 acc = (f4)0.0f;

    #pragma unroll
    for (int k = 0; k < 8; ++k) {
        const int i = ibase + k;
        const int f = tg - (i << 7);     // in [0,1020], multiple of 4
        // OOB waveguides (first/last blocks only): weight already 0 in LDS;
        // clamp the address so the discarded load stays in-bounds. Branch-free.
        const int ic = i < 0 ? 0 : (i > NWG - 1 ? NWG - 1 : i);
        const float* ey = Ey + (size_t)ic * (MODES * EY_SIZE) + f;
        const int wb = (dibase + k) * MODES;
        #pragma unroll
        for (int m = 0; m < MODES; ++m) {
            const f4 e = __builtin_nontemporal_load(
                reinterpret_cast<const f4*>(ey + m * EY_SIZE));
            acc += w[wb + m] * e;
        }
    }

    *reinterpret_cast<f4*>(En + g0) = acc;
}

extern "C" void kernel_launch(void* const* d_in, const int* in_sizes, int n_in,
                              void* d_out, int out_size, void* d_ws, size_t ws_size,
                              hipStream_t stream) {
    // inputs (setup_inputs order): hs (unused), U, neff, Ey — all float32
    const float* U    = (const float*)d_in[1];
    const float* neff = (const float*)d_in[2];
    const float* Ey   = (const float*)d_in[3];
    float* En = (float*)d_out;

    gen_en_gather3<<<NBLOCKS, 256, 0, stream>>>(U, neff, Ey, En);
}

// Round 4
// 35.314 us; speedup vs baseline: 1.1736x; 1.0798x over previous
//
#include <hip/hip_runtime.h>

// gen_En: En[g] = sum over waveguides i covering g of sum_m eta[i,m]*U[i,m]*Ey[i,m,f]
//   eta = neff/(neff+1), f = g - 64 - 128*i, window 1024, stride 128 (overlap 8).
// Gather formulation: each Ey element is consumed exactly once, no atomics.
//
// ROUND-1 REVERT (best measured: 35.4 us = 5.8 TB/s effective, 92% of the
// 6.29 TB/s float4-copy ceiling). Round 2 (2 float4/thread, 513 blocks) and
// round 3 (const-8 unroll + nontemporal) both regressed: TLP (4100 waves,
// 16 waves/CU) + compact variable-bound loop beats ILP/unroll variants.

#define MODES 6
#define RES 128
#define NWG 8192
#define EY_SIZE 1024
#define TOTAL_SIZE ((NWG + 8) * RES)   // 1,049,600

// 256 threads/block, 4 outputs/thread -> 1024 outputs/block, 1025 blocks exact.
__global__ __launch_bounds__(256) void gen_en_gather(
    const float* __restrict__ U,
    const float* __restrict__ neff,
    const float* __restrict__ Ey,
    float* __restrict__ En)
{
    // Per-block weights: at most 16 waveguides touch this block's 1024 outputs.
    __shared__ float w[96];

    const int g_blk = blockIdx.x << 10;          // 1024 outputs per block
    const int tb = g_blk - 64;
    int i_lo_blk = (tb >= 0 ? (tb >> 7) : -1) - 7;
    if (i_lo_blk < 0) i_lo_blk = 0;
    int i_hi_blk = (g_blk + 1023 - 64) >> 7;     // always >= 0
    if (i_hi_blk > NWG - 1) i_hi_blk = NWG - 1;

    const int t = threadIdx.x;
    if (t < 96) {
        const int di = t / 6;
        const int m  = t - di * 6;
        const int i  = i_lo_blk + di;
        float v = 0.0f;
        if (i <= i_hi_blk) {
            const float nf = neff[i * MODES + m];
            v = nf / (nf + 1.0f) * U[i * MODES + m];   // eta * U
        }
        w[t] = v;
    }
    __syncthreads();

    const int g0 = g_blk + (t << 2);             // multiple of 4
    const int tg = g0 - 64;                      // multiple of 4
    int ihi = (tg >= 0) ? (tg >> 7) : -1;
    int ilo = ihi - 7;
    if (ilo < 0) ilo = 0;
    if (ihi > NWG - 1) ihi = NWG - 1;

    float4 acc = make_float4(0.0f, 0.0f, 0.0f, 0.0f);

    for (int i = ilo; i <= ihi; ++i) {
        const int f0 = tg - (i << 7);            // in [0,1020], multiple of 4
        const float* ey = Ey + (size_t)i * (MODES * EY_SIZE) + f0;
        const int wbase = (i - i_lo_blk) * MODES;
        #pragma unroll
        for (int m = 0; m < MODES; ++m) {
            const float4 e = *reinterpret_cast<const float4*>(ey + m * EY_SIZE);
            const float wm = w[wbase + m];
            acc.x += wm * e.x;
            acc.y += wm * e.y;
            acc.z += wm * e.z;
            acc.w += wm * e.w;
        }
    }

    *reinterpret_cast<float4*>(En + g0) = acc;   // covers every output element:
                                                 // zero where no window overlaps
}

extern "C" void kernel_launch(void* const* d_in, const int* in_sizes, int n_in,
                              void* d_out, int out_size, void* d_ws, size_t ws_size,
                              hipStream_t stream) {
    // inputs (setup_inputs order): hs (unused), U, neff, Ey — all float32
    const float* U    = (const float*)d_in[1];
    const float* neff = (const float*)d_in[2];
    const float* Ey   = (const float*)d_in[3];
    float* En = (float*)d_out;

    const int blocks = TOTAL_SIZE / 1024;        // 1025, exact tiling
    gen_en_gather<<<blocks, 256, 0, stream>>>(U, neff, Ey, En);
}